// Round 10
// baseline (275.148 us; speedup 1.0000x reference)
//
#include <hip/hip_runtime.h>
#include <hip/hip_bf16.h>
#include <stdint.h>

// Problem constants (B,T,C,H,D) = (4,2048,1024,16,64)
#define Bb 4
#define Tt 2048
#define Cc 1024
#define Hh 16
#define Dd 64

using bf16x8 = __bf16 __attribute__((ext_vector_type(8)));
using f32x4  = float  __attribute__((ext_vector_type(4)));
using f32x2  = float  __attribute__((ext_vector_type(2)));
using f32x16 = float  __attribute__((ext_vector_type(16)));
typedef unsigned short u16;
typedef unsigned int   u32;

#if defined(__has_builtin) && __has_builtin(__builtin_amdgcn_exp2f)
#define EXP2F(x) __builtin_amdgcn_exp2f(x)
#else
#define EXP2F(x) exp2f(x)
#endif

#if defined(__has_builtin) && __has_builtin(__builtin_amdgcn_permlane32_swap)
#define PERMLANE32_SWAP(a, b)                                          \
  do {                                                                 \
    auto _r = __builtin_amdgcn_permlane32_swap((a), (b), false, false);\
    (a) = _r[0]; (b) = _r[1];                                          \
  } while (0)
#else
#define PERMLANE32_SWAP(a, b) \
  asm volatile("v_permlane32_swap_b32 %0, %1" : "+v"(a), "+v"(b))
#endif

__device__ __forceinline__ unsigned cvt_pk_bf16(float lo, float hi) {
  unsigned r;
  asm("v_cvt_pk_bf16_f32 %0, %1, %2" : "=v"(r) : "v"(lo), "v"(hi));
  return r;
}

__device__ __forceinline__ u16 f32_to_bf16(float f) {
  union { float f; unsigned u; } v; v.f = f;
  unsigned r = v.u + 0x7fffu + ((v.u >> 16) & 1u);  // RNE
  return (u16)(r >> 16);
}

// async global->LDS, 16B per lane. LDS dest = wave-uniform base + lane*16.
__device__ __forceinline__ void gl2lds16(const u16* g, u16* l) {
  __builtin_amdgcn_global_load_lds(
      (const __attribute__((address_space(1))) u32*)g,
      (__attribute__((address_space(3))) u32*)l, 16, 0, 0);
}

// ---------------- fused cast: x (8Mi) + Wq|Wk|Wv|Wo (4x1Mi) -> ws bf16 -------
__global__ void cast_all(const float* __restrict__ x,
                         const float* __restrict__ w0, const float* __restrict__ w1,
                         const float* __restrict__ w2, const float* __restrict__ w3,
                         u16* __restrict__ out) {
  size_t e = ((size_t)blockIdx.x * blockDim.x + threadIdx.x) * 4;
  size_t hi = e >> 20;   // 0-7: x, 8-11: weights
  const float* src;
  if (hi < 8) {
    src = x + e;
  } else {
    size_t off = e & 1048575u;
    src = (hi == 8 ? w0 : hi == 9 ? w1 : hi == 10 ? w2 : w3) + off;
  }
  float4 v = *reinterpret_cast<const float4*>(src);
  ushort4 o;
  o.x = f32_to_bf16(v.x); o.y = f32_to_bf16(v.y);
  o.z = f32_to_bf16(v.z); o.w = f32_to_bf16(v.w);
  *reinterpret_cast<ushort4*>(out + e) = o;
}

// ---------------- 8-phase GEMM: BM=256 BN=128 BK=64, 512 thr, counted vmcnt --
__global__ __launch_bounds__(512, 2)
void gemm8(const u16* __restrict__ A, const u16* __restrict__ Bm,
           const float* __restrict__ b0, const float* __restrict__ b1,
           const float* __restrict__ b2,
           u16* __restrict__ o0, u16* __restrict__ o1, u16* __restrict__ vtout,
           float* __restrict__ of32, float qscl, int isqkv)
{
  constexpr int K = Cc;
  __shared__ alignas(16) u16 smem16[49152];
  const int tid = threadIdx.x;
  const int wave = tid >> 6, lane = tid & 63;
  const int fr = lane & 15, qd = lane >> 4, sw = fr & 7;
  const int wr = wave >> 1, wc = wave & 1;
  const int lid = blockIdx.x;
  const int xcd = lid & 7, idx = lid >> 3;
  const int bx = xcd * 4 + (idx & 3), by = idx >> 2;
  const int row0 = bx * 256, col0 = by * 128;

  const u16* pA = A  + (size_t)(row0 + (lane >> 3)) * K + (((lane & 7) ^ (lane >> 3)) << 3);
  const u16* pB = Bm + (size_t)(col0 + (lane >> 3)) * K + (((lane & 7) ^ (lane >> 3)) << 3);

  f32x4 acc[4][4] = {};
  bf16x8 bfr[4][2];

#define STG_A(BUF, H, T) do {                                              \
    gl2lds16(pA + (size_t)((H)*128 + wave*16) * K + (T)*64,                \
             smem16 + (BUF)*24576 + ((H)*128 + wave*16) * 64);             \
    gl2lds16(pA + (size_t)((H)*128 + wave*16 + 8) * K + (T)*64,            \
             smem16 + (BUF)*24576 + ((H)*128 + wave*16 + 8) * 64);         \
  } while (0)
#define STG_B(BUF, T) do {                                                 \
    gl2lds16(pB + (size_t)(wave*16) * K + (T)*64,                          \
             smem16 + (BUF)*24576 + 16384 + (wave*16) * 64);               \
    gl2lds16(pB + (size_t)(wave*16 + 8) * K + (T)*64,                      \
             smem16 + (BUF)*24576 + 16384 + (wave*16 + 8) * 64);           \
  } while (0)
#define LDA(BUF, Q, KK) (*reinterpret_cast<const bf16x8*>(                 \
    &smem16[(BUF)*24576 + (wr*64 + (Q)*16 + fr) * 64 + ((((KK)*4 + qd) ^ sw) << 3)]))
#define LDB(BUF, J, KK) (*reinterpret_cast<const bf16x8*>(                 \
    &smem16[(BUF)*24576 + 16384 + (wc*64 + (J)*16 + fr) * 64 + ((((KK)*4 + qd) ^ sw) << 3)]))
#define GATE2 asm volatile("s_waitcnt vmcnt(2)" ::: "memory")
#define GATE0 asm volatile("s_waitcnt vmcnt(0)" ::: "memory")
#define GNONE
#define SBAR do { asm volatile("" ::: "memory");                           \
    __builtin_amdgcn_s_barrier(); asm volatile("" ::: "memory"); } while (0)

#define PH(Q, BUF, GATE, ...) do {                                         \
    bf16x8 af0 = LDA(BUF, Q, 0), af1 = LDA(BUF, Q, 1);                     \
    if ((Q) == 0) {                                                        \
      bfr[0][0] = LDB(BUF, 0, 0); bfr[0][1] = LDB(BUF, 0, 1);              \
      bfr[1][0] = LDB(BUF, 1, 0); bfr[1][1] = LDB(BUF, 1, 1);              \
      bfr[2][0] = LDB(BUF, 2, 0); bfr[2][1] = LDB(BUF, 2, 1);              \
      bfr[3][0] = LDB(BUF, 3, 0); bfr[3][1] = LDB(BUF, 3, 1);              \
    }                                                                      \
    __VA_ARGS__;                                                           \
    asm volatile("" ::: "memory");                                         \
    __builtin_amdgcn_s_barrier();                                          \
    asm volatile("s_waitcnt lgkmcnt(0)" ::: "memory");                     \
    __builtin_amdgcn_sched_barrier(0);                                     \
    __builtin_amdgcn_s_setprio(1);                                         \
    acc[Q][0] = __builtin_amdgcn_mfma_f32_16x16x32_bf16(af0, bfr[0][0], acc[Q][0], 0, 0, 0); \
    acc[Q][0] = __builtin_amdgcn_mfma_f32_16x16x32_bf16(af1, bfr[0][1], acc[Q][0], 0, 0, 0); \
    acc[Q][1] = __builtin_amdgcn_mfma_f32_16x16x32_bf16(af0, bfr[1][0], acc[Q][1], 0, 0, 0); \
    acc[Q][1] = __builtin_amdgcn_mfma_f32_16x16x32_bf16(af1, bfr[1][1], acc[Q][1], 0, 0, 0); \
    acc[Q][2] = __builtin_amdgcn_mfma_f32_16x16x32_bf16(af0, bfr[2][0], acc[Q][2], 0, 0, 0); \
    acc[Q][2] = __builtin_amdgcn_mfma_f32_16x16x32_bf16(af1, bfr[2][1], acc[Q][2], 0, 0, 0); \
    acc[Q][3] = __builtin_amdgcn_mfma_f32_16x16x32_bf16(af0, bfr[3][0], acc[Q][3], 0, 0, 0); \
    acc[Q][3] = __builtin_amdgcn_mfma_f32_16x16x32_bf16(af1, bfr[3][1], acc[Q][3], 0, 0, 0); \
    __builtin_amdgcn_s_setprio(0);                                         \
    GATE;                                                                  \
    SBAR;                                                                  \
  } while (0)

  STG_B(0, 0); STG_A(0, 0, 0); STG_A(0, 1, 0); STG_B(1, 1);
  GATE2;
  SBAR;

#pragma unroll 1
  for (int i = 0; i < 8; ++i) {
    const int t1 = 2 * i + 1, t2 = 2 * i + 2, t3 = 2 * i + 3;
    const bool g = i < 7;
    PH(0, 0, GNONE, STG_A(1, 0, t1));
    PH(1, 0, GNONE, STG_A(1, 1, t1));
    PH(2, 0, GNONE, if (g) STG_B(0, t2));
    if (g) { PH(3, 0, GATE2, ); } else { PH(3, 0, GATE0, ); }
    PH(0, 1, GNONE, if (g) STG_A(0, 0, t2));
    PH(1, 1, GNONE, if (g) STG_A(0, 1, t2));
    PH(2, 1, GNONE, if (g) STG_B(1, t3));
    PH(3, 1, GATE2, );
  }
#undef PH
#undef STG_A
#undef STG_B
#undef LDA
#undef LDB

  const int colL0 = col0 & 1023;
  if (!isqkv) {
#pragma unroll
    for (int j = 0; j < 4; ++j) {
      int col = col0 + wc * 64 + j * 16 + fr;
      float bv = b0[col];
#pragma unroll
      for (int m = 0; m < 4; ++m) {
        int rowb = row0 + wr * 64 + m * 16 + qd * 4;
#pragma unroll
        for (int r = 0; r < 4; ++r)
          of32[(size_t)(rowb + r) * Cc + col] = acc[m][j][r] + bv;
      }
    }
    return;
  }
  const int seg = col0 >> 10;   // 0=q 1=k 2=v
  const float* bias = (seg == 0) ? b0 : ((seg == 1) ? b1 : b2);
  const float scale = (seg == 0) ? qscl : 1.0f;
  if (seg < 2) {
    u16* outp = (seg == 0) ? o0 : o1;
#pragma unroll
    for (int j = 0; j < 4; ++j) {
      int col = colL0 + wc * 64 + j * 16 + fr;
      float bv = bias[col];
#pragma unroll
      for (int m = 0; m < 4; ++m) {
        int rowb = row0 + wr * 64 + m * 16 + qd * 4;
#pragma unroll
        for (int r = 0; r < 4; ++r)
          outp[(size_t)(rowb + r) * Cc + col] = f32_to_bf16((acc[m][j][r] + bv) * scale);
      }
    }
  } else {
#pragma unroll
    for (int j = 0; j < 4; ++j) {
      int lc = wc * 64 + j * 16 + fr;
      float bv = bias[colL0 + lc];
#pragma unroll
      for (int m = 0; m < 4; ++m) {
        int lr = wr * 64 + m * 16 + qd * 4;
#pragma unroll
        for (int r = 0; r < 4; ++r)
          smem16[lc * 264 + lr + r] = f32_to_bf16(acc[m][j][r] + bv);
      }
    }
    __syncthreads();
    int lc = tid >> 2, quarter = tid & 3;
    int col = colL0 + lc;                 // = h*64 + d
    int h = col >> 6, d = col & 63;
    int bb = row0 >> 11, t0 = (row0 & 2047) + quarter * 64;
    u16* dst = vtout + ((size_t)(bb * Hh + h) * Dd + d) * Tt + t0;
    const u16* src = &smem16[lc * 264 + quarter * 64];
#pragma unroll
    for (int g2 = 0; g2 < 8; ++g2)
      *reinterpret_cast<uint4*>(dst + g2 * 8) = *reinterpret_cast<const uint4*>(src + g2 * 8);
  }
}

// ---------------- attention: 128-q blocks, wave owns full 64-key tile --------
// Wave w owns q-tile qt=w (32 rows of the 128-row block) and ALL 64 keys per
// KV tile: 2 independent QK chains (s0 keys 0-31, s1 keys 32-63), 16 MFMA per
// tile per wave. No cross-wave O combine (each wave's Oacc is complete).
// Staging identical to the proven KVBLK=64 kernel; K/V re-reads halve.
__global__ __launch_bounds__(256, 3)
void attn_kernel(const u16* __restrict__ Q, const u16* __restrict__ Kmat,
                 const u16* __restrict__ VT, u16* __restrict__ O) {
  // dbuf: buf b at smem + b*16384: Ks[64][64] (8KB, chunk^(key&7)),
  //                                Vs[64][64] (8KB, chunk^(d&7))
  // epilogue aliases: OfT[64][132] f32 (33792B) + Qs[128] f32 (512B)
  __shared__ alignas(16) unsigned char smem[36864];
  float* OfT = (float*)smem;
  float* Qs  = (float*)(smem + 33792);

  const int tid = threadIdx.x, wave = tid >> 6, lane = tid & 63;
  const int l31 = lane & 31, hi = lane >> 5, k7 = l31 & 7;
  const int bh = blockIdx.x, qt0 = blockIdx.y;   // qt0: 128-row q block
  const int b = bh >> 4, h = bh & 15;
  const size_t base = (size_t)b * Tt * Cc + (size_t)h * Dd;
  const size_t vtb = (size_t)bh * Dd * Tt;

  // Q fragments (wave's qt = wave): B[k=d][n=q], lane holds
  // Q[q = wave*32 + l31][d = c*16 + hi*8 + j]
  bf16x8 qb[4];
  {
    const u16* qp = Q + base + (size_t)(qt0 * 128 + wave * 32 + l31) * Cc + hi * 8;
#pragma unroll
    for (int c = 0; c < 4; ++c)
      qb[c] = *reinterpret_cast<const bf16x8*>(qp + c * 16);
  }

  f32x16 Oacc[2] = {};   // [dh]: O[q = wave*32 + crow][d = dh*32 + l31], complete
  f32x2 sacc = {0.f, 0.f};

  // staging: instr (w,c) covers 8 LDS rows (w*16 + c*8 + L>>3), chunk (L&7),
  // source chunk pre-swizzled (L&7)^(L>>3).
  const u16* pK = Kmat + base + (size_t)(wave * 16 + (lane >> 3)) * Cc +
                  (((lane & 7) ^ (lane >> 3)) << 3);
  const u16* pV = VT + vtb + (size_t)(wave * 16 + (lane >> 3)) * Tt +
                  (((lane & 7) ^ (lane >> 3)) << 3);

  auto STAGE = [&](int buf, int kt) {
    u16* Kd = (u16*)(smem + (buf << 14)) + wave * 1024;
    u16* Vd = Kd + 4096;
    const u16* pk = pK + (size_t)kt * Cc;
    const u16* pv = pV + kt;
#pragma unroll
    for (int c = 0; c < 2; ++c) {
      gl2lds16(pk + (size_t)(c * 8) * Cc, Kd + c * 512);
      gl2lds16(pv + (size_t)(c * 8) * Tt, Vd + c * 512);
    }
  };

  STAGE(0, 0);
  __syncthreads();

  int cur = 0;
#pragma unroll 1
  for (int t = 0; t < 32; ++t) {
    if (t < 31) STAGE(cur ^ 1, (t + 1) << 6);

    const u16* Ks = (const u16*)(smem + (cur << 14));
    const u16* Vs = Ks + 4096;

    // K A-frags, both key halves: A[row=key][k = c*16 + hi*8 + j]
    bf16x8 kl[4], kh_[4];
#pragma unroll
    for (int c = 0; c < 4; ++c) {
      int off = (((c << 1) + hi) ^ k7) << 3;
      kl[c]  = *reinterpret_cast<const bf16x8*>(&Ks[l31 * 64 + off]);
      kh_[c] = *reinterpret_cast<const bf16x8*>(&Ks[(32 + l31) * 64 + off]);
    }
    // V B-frags, all 4 key-slots: B[k = ks*16 + hi*8 + j][n = d = dh*32 + l31]
    bf16x8 vb[4][2];
#pragma unroll
    for (int ks = 0; ks < 4; ++ks)
#pragma unroll
      for (int dh = 0; dh < 2; ++dh) {
        int drow = dh * 32 + l31;
        int ch = ks * 2 + hi;
        vb[ks][dh] = *reinterpret_cast<const bf16x8*>(
            &Vs[drow * 64 + ((ch ^ (drow & 7)) << 3)]);
      }

    __builtin_amdgcn_s_setprio(1);

    // two independent QK chains: s0 = keys 0..31, s1 = keys 32..63
    f32x16 s0 = {}, s1 = {};
#pragma unroll
    for (int c = 0; c < 4; ++c) {
      s0 = __builtin_amdgcn_mfma_f32_32x32x16_bf16(kl[c],  qb[c], s0, 0, 0, 0);
      s1 = __builtin_amdgcn_mfma_f32_32x32x16_bf16(kh_[c], qb[c], s1, 0, 0, 0);
    }

    unsigned pkA[8], pkB[8];
#pragma unroll
    for (int i = 0; i < 8; ++i) {
      float p0 = EXP2F(s0[2 * i]), p1 = EXP2F(s0[2 * i + 1]);
      float p2 = EXP2F(s1[2 * i]), p3 = EXP2F(s1[2 * i + 1]);
      sacc += (f32x2){p0, p1};
      sacc += (f32x2){p2, p3};
      pkA[i] = cvt_pk_bf16(p0, p1);
      pkB[i] = cvt_pk_bf16(p2, p3);
    }
    unsigned a0 = pkA[0], a1 = pkA[1], a2 = pkA[2], a3 = pkA[3];
    unsigned b0 = pkA[4], b1 = pkA[5], b2 = pkA[6], b3 = pkA[7];
    unsigned c0 = pkB[0], c1 = pkB[1], c2 = pkB[2], c3 = pkB[3];
    unsigned d0 = pkB[4], d1 = pkB[5], d2 = pkB[6], d3 = pkB[7];
    PERMLANE32_SWAP(a0, a2); PERMLANE32_SWAP(a1, a3);
    PERMLANE32_SWAP(b0, b2); PERMLANE32_SWAP(b1, b3);
    PERMLANE32_SWAP(c0, c2); PERMLANE32_SWAP(c1, c3);
    PERMLANE32_SWAP(d0, d2); PERMLANE32_SWAP(d1, d3);
    union { unsigned u[4]; bf16x8 v; } p0_, p1_, p2_, p3_;
    p0_.u[0] = a0; p0_.u[1] = a1; p0_.u[2] = a2; p0_.u[3] = a3;  // keys 0..15
    p1_.u[0] = b0; p1_.u[1] = b1; p1_.u[2] = b2; p1_.u[3] = b3;  // keys 16..31
    p2_.u[0] = c0; p2_.u[1] = c1; p2_.u[2] = c2; p2_.u[3] = c3;  // keys 32..47
    p3_.u[0] = d0; p3_.u[1] = d1; p3_.u[2] = d2; p3_.u[3] = d3;  // keys 48..63

    Oacc[0] = __builtin_amdgcn_mfma_f32_32x32x16_bf16(p0_.v, vb[0][0], Oacc[0], 0, 0, 0);
    Oacc[1] = __builtin_amdgcn_mfma_f32_32x32x16_bf16(p0_.v, vb[0][1], Oacc[1], 0, 0, 0);
    Oacc[0] = __builtin_amdgcn_mfma_f32_32x32x16_bf16(p1_.v, vb[1][0], Oacc[0], 0, 0, 0);
    Oacc[1] = __builtin_amdgcn_mfma_f32_32x32x16_bf16(p1_.v, vb[1][1], Oacc[1], 0, 0, 0);
    Oacc[0] = __builtin_amdgcn_mfma_f32_32x32x16_bf16(p2_.v, vb[2][0], Oacc[0], 0, 0, 0);
    Oacc[1] = __builtin_amdgcn_mfma_f32_32x32x16_bf16(p2_.v, vb[2][1], Oacc[1], 0, 0, 0);
    Oacc[0] = __builtin_amdgcn_mfma_f32_32x32x16_bf16(p3_.v, vb[3][0], Oacc[0], 0, 0, 0);
    Oacc[1] = __builtin_amdgcn_mfma_f32_32x32x16_bf16(p3_.v, vb[3][1], Oacc[1], 0, 0, 0);

    __builtin_amdgcn_s_setprio(0);

    __syncthreads();
    cur ^= 1;
  }

  // ---- denominators (full 64-key rows already in-wave) ----
  {
    float s = sacc[0] + sacc[1];
    s += __shfl_xor(s, 32, 64);
    if (hi == 0) Qs[wave * 32 + l31] = s;
  }

  // ---- each wave writes its complete O^T slice (disjoint q ranges) ----
#pragma unroll
  for (int dh = 0; dh < 2; ++dh) {
    int d = dh * 32 + l31;
    float* rowp = &OfT[d * 132 + wave * 32 + hi * 4];
#pragma unroll
    for (int g = 0; g < 4; ++g) {
      f32x4 v;
      v[0] = Oacc[dh][g * 4 + 0]; v[1] = Oacc[dh][g * 4 + 1];
      v[2] = Oacc[dh][g * 4 + 2]; v[3] = Oacc[dh][g * 4 + 3];
      *reinterpret_cast<f32x4*>(rowp + g * 8) = v;   // q = wave*32+4*hi+8g+{0..3}
    }
  }
  __syncthreads();

  // ---- normalize + store: thread = (q = tid>>1, d-half = tid&1) ----
  {
    int q = tid >> 1, dh2 = tid & 1;
    float linv = 1.0f / Qs[q];
    alignas(16) u16 tmp[32];
#pragma unroll
    for (int i = 0; i < 32; ++i)
      tmp[i] = f32_to_bf16(OfT[(dh2 * 32 + i) * 132 + q] * linv);
    u16* op = O + base + (size_t)(qt0 * 128 + q) * Cc + dh2 * 32;
#pragma unroll
    for (int g = 0; g < 4; ++g)
      *reinterpret_cast<uint4*>(op + g * 8) = *reinterpret_cast<const uint4*>(tmp + g * 8);
  }
}

extern "C" void kernel_launch(void* const* d_in, const int* in_sizes, int n_in,
                              void* d_out, int out_size, void* d_ws, size_t ws_size,
                              hipStream_t stream) {
  const float* x  = (const float*)d_in[0];
  const float* Wq = (const float*)d_in[1];
  const float* bq = (const float*)d_in[2];
  const float* Wk = (const float*)d_in[3];
  const float* bk = (const float*)d_in[4];
  const float* Wv = (const float*)d_in[5];
  const float* bv = (const float*)d_in[6];
  const float* Wo = (const float*)d_in[7];
  const float* bo = (const float*)d_in[8];

  const size_t NX = (size_t)Bb * Tt * Cc;  // 8388608
  const size_t NW = (size_t)Cc * Cc;       // 1048576

  u16* ws  = (u16*)d_ws;
  u16* xb  = ws;
  u16* wqb = ws + NX;     // wq|wk|wv contiguous -> the fused [3072,1024] B matrix
  u16* wkb = wqb + NW;
  u16* wvb = wkb + NW;
  u16* wob = wvb + NW;
  u16* qb  = wob + NW;
  u16* kb  = qb + NX;
  u16* vtb = kb + NX;
  u16* attnb = xb;  // alias: x dead once projections are done

  cast_all<<<dim3(12288), 256, 0, stream>>>(x, Wq, Wk, Wv, Wo, ws);

  const float QSCL = 0.125f * 1.44269504f;  // 1/sqrt(D) * log2(e), folded into Q
  gemm8<<<dim3(768), 512, 0, stream>>>(xb, wqb, bq, bk, bv, qb, kb, vtb,
                                       nullptr, QSCL, 1);

  attn_kernel<<<dim3(Bb * Hh, Tt / 128), 256, 0, stream>>>(qb, kb, vtb, attnb);

  gemm8<<<dim3(256), 512, 0, stream>>>(attnb, wob, bo, nullptr, nullptr,
                                       nullptr, nullptr, nullptr,
                                       (float*)d_out, 1.0f, 0);
}

// Round 12
// 261.947 us; speedup vs baseline: 1.0504x; 1.0504x over previous
//
#include <hip/hip_runtime.h>
#include <hip/hip_bf16.h>
#include <stdint.h>

// Problem constants (B,T,C,H,D) = (4,2048,1024,16,64)
#define Bb 4
#define Tt 2048
#define Cc 1024
#define Hh 16
#define Dd 64

using bf16x8 = __bf16 __attribute__((ext_vector_type(8)));
using f32x4  = float  __attribute__((ext_vector_type(4)));
using f32x2  = float  __attribute__((ext_vector_type(2)));
using f32x16 = float  __attribute__((ext_vector_type(16)));
typedef unsigned short u16;
typedef unsigned int   u32;

#if defined(__has_builtin) && __has_builtin(__builtin_amdgcn_exp2f)
#define EXP2F(x) __builtin_amdgcn_exp2f(x)
#else
#define EXP2F(x) exp2f(x)
#endif

#if defined(__has_builtin) && __has_builtin(__builtin_amdgcn_permlane32_swap)
#define PERMLANE32_SWAP(a, b)                                          \
  do {                                                                 \
    auto _r = __builtin_amdgcn_permlane32_swap((a), (b), false, false);\
    (a) = _r[0]; (b) = _r[1];                                          \
  } while (0)
#else
#define PERMLANE32_SWAP(a, b) \
  asm volatile("v_permlane32_swap_b32 %0, %1" : "+v"(a), "+v"(b))
#endif

// HW packed f32x2 -> bf16x2 (RNE). No builtin on gfx950; T12 recipe.
__device__ __forceinline__ unsigned cvt_pk_bf16(float lo, float hi) {
  unsigned r;
  asm("v_cvt_pk_bf16_f32 %0, %1, %2" : "=v"(r) : "v"(lo), "v"(hi));
  return r;
}

__device__ __forceinline__ u16 f32_to_bf16(float f) {
  union { float f; unsigned u; } v; v.f = f;
  unsigned r = v.u + 0x7fffu + ((v.u >> 16) & 1u);  // RNE
  return (u16)(r >> 16);
}

// async global->LDS, 16B per lane. LDS dest = wave-uniform base + lane*16.
__device__ __forceinline__ void gl2lds16(const u16* g, u16* l) {
  __builtin_amdgcn_global_load_lds(
      (const __attribute__((address_space(1))) u32*)g,
      (__attribute__((address_space(3))) u32*)l, 16, 0, 0);
}

// ---------------- fused cast: x (8Mi) + Wq|Wk|Wv|Wo (4x1Mi) -> ws bf16 -------
// Outputs are contiguous in ws (xb at 0, then wqb..wob), so dst = ws + e.
__global__ void cast_all(const float* __restrict__ x,
                         const float* __restrict__ w0, const float* __restrict__ w1,
                         const float* __restrict__ w2, const float* __restrict__ w3,
                         u16* __restrict__ out) {
  size_t e = ((size_t)blockIdx.x * blockDim.x + threadIdx.x) * 4;
  size_t hi = e >> 20;   // 0-7: x, 8-11: weights
  const float* src;
  if (hi < 8) {
    src = x + e;
  } else {
    size_t off = e & 1048575u;
    src = (hi == 8 ? w0 : hi == 9 ? w1 : hi == 10 ? w2 : w3) + off;
  }
  float4 v = *reinterpret_cast<const float4*>(src);
  ushort4 o;
  o.x = f32_to_bf16(v.x); o.y = f32_to_bf16(v.y);
  o.z = f32_to_bf16(v.z); o.w = f32_to_bf16(v.w);
  *reinterpret_cast<ushort4*>(out + e) = o;
}

// ---------------- fused QKV projection GEMM (BK=64, swizzled LDS, T1) --------
// 1-D grid 1536, decode: xcd = lid&7 owns bx slab [xcd*8, xcd*8+8) (2MB of A,
// L2-resident per XCD); LDS chunks XOR-swizzled (chunk16B ^ row&7) via
// pre-swizzled global source -> conflict-free ds_read_b128 (2-way, free).
__global__ __launch_bounds__(256, 3)
void gemm_qkv(const u16* __restrict__ A, const u16* __restrict__ Bqkv,
              const float* __restrict__ bq, const float* __restrict__ bk,
              const float* __restrict__ bv,
              u16* __restrict__ qout, u16* __restrict__ kout, u16* __restrict__ vtout,
              float qscl)
{
  constexpr int K = Cc, BK = 64, LDT = 136;
  __shared__ alignas(16) u16 smem[128 * LDT];   // staging 32KB; transpose 34.8KB
  u16* As = smem;               // [128][64] swizzled
  u16* Bs = smem + 128 * 64;    // [128][64] swizzled
  const int tid  = threadIdx.x;
  const int wave = tid >> 6, lane = tid & 63;
  const int lid = blockIdx.x;                    // [0,1536)
  const int xcd = lid & 7, cch = lid >> 3;       // T1: bx slab per XCD
  const int bx = xcd * 8 + (cch & 7), by = cch >> 3;
  const int row0 = bx * 128, col0 = by * 128;    // col0 in [0,3072)
  const int seg  = col0 >> 10;                   // 0=q 1=k 2=v
  const int wm = (wave & 1) * 64, wn = (wave >> 1) * 64;
  const int fr = lane & 15, qd = lane >> 4;
  const int srow = lane >> 3;                    // 0..7
  const int scol = ((lane & 7) ^ srow) << 3;     // pre-swizzled source chunk

  f32x4 acc[4][4] = {};
  const u16* pA = A    + (size_t)(row0 + wave * 32 + srow) * K + scol;
  const u16* pB = Bqkv + (size_t)(col0 + wave * 32 + srow) * K + scol;

  for (int k0 = 0; k0 < K; k0 += BK) {
#pragma unroll
    for (int c = 0; c < 4; ++c) {
      gl2lds16(pA + (size_t)(c * 8) * K + k0, &As[(wave * 32 + c * 8) * 64]);
      gl2lds16(pB + (size_t)(c * 8) * K + k0, &Bs[(wave * 32 + c * 8) * 64]);
    }
    __syncthreads();
#pragma unroll
    for (int kk = 0; kk < 2; ++kk) {
      bf16x8 af[4], bf[4];
#pragma unroll
      for (int i = 0; i < 4; ++i) {
        int ra = wm + i * 16 + fr;
        af[i] = *reinterpret_cast<const bf16x8*>(
            &As[ra * 64 + (((kk * 4 + qd) ^ (ra & 7)) << 3)]);
        int rb = wn + i * 16 + fr;
        bf[i] = *reinterpret_cast<const bf16x8*>(
            &Bs[rb * 64 + (((kk * 4 + qd) ^ (rb & 7)) << 3)]);
      }
#pragma unroll
      for (int i = 0; i < 4; ++i)
#pragma unroll
        for (int j = 0; j < 4; ++j)
          acc[i][j] = __builtin_amdgcn_mfma_f32_16x16x32_bf16(af[i], bf[j], acc[i][j], 0, 0, 0);
    }
    __syncthreads();
  }

  const float* bias = (seg == 0) ? bq : ((seg == 1) ? bk : bv);
  const float scale = (seg == 0) ? qscl : 1.0f;
  const int colL0 = col0 & 1023;   // local column base within the segment

  if (seg < 2) {
    u16* outp = (seg == 0) ? qout : kout;
#pragma unroll
    for (int j = 0; j < 4; ++j) {
      int col = colL0 + wn + j * 16 + fr;
      float bvv = bias[col];
#pragma unroll
      for (int i = 0; i < 4; ++i) {
        int rowb = row0 + wm + i * 16 + (lane >> 4) * 4;
#pragma unroll
        for (int r = 0; r < 4; ++r)
          outp[(size_t)(rowb + r) * Cc + col] = f32_to_bf16((acc[i][j][r] + bvv) * scale);
      }
    }
  } else {
    // V: C-tile -> smem [col][row] bf16 -> coalesced store into VT[B,H,D,T]
    __syncthreads();
#pragma unroll
    for (int j = 0; j < 4; ++j) {
      int lc = wn + j * 16 + fr;
      float bvv = bias[colL0 + lc];
#pragma unroll
      for (int i = 0; i < 4; ++i) {
        int lr = wm + i * 16 + (lane >> 4) * 4;
#pragma unroll
        for (int r = 0; r < 4; ++r)
          smem[lc * LDT + lr + r] = f32_to_bf16(acc[i][j][r] + bvv);
      }
    }
    __syncthreads();
    int lc = tid >> 1, seg2 = tid & 1;
    int col = colL0 + lc;                 // = h*64 + d
    int h = col >> 6, d = col & 63;
    int bb = row0 >> 11, t0 = (row0 & 2047) + seg2 * 64;
    u16* dst = vtout + ((size_t)(bb * Hh + h) * Dd + d) * Tt + t0;
    const u16* src = &smem[lc * LDT + seg2 * 64];
#pragma unroll
    for (int g = 0; g < 8; ++g)
      *reinterpret_cast<uint4*>(dst + g * 8) = *reinterpret_cast<const uint4*>(src + g * 8);
  }
}

// ---------------- output GEMM (BK=64, swizzled LDS, T1) ----------------------
__global__ __launch_bounds__(256, 3)
void gemm_out(const u16* __restrict__ A, const u16* __restrict__ Bw,
              const float* __restrict__ bias, float* __restrict__ Cout,
              int M, int N, int K)
{
  constexpr int BK = 64;
  __shared__ alignas(16) u16 As[128 * 64];
  __shared__ alignas(16) u16 Bs[128 * 64];
  const int tid  = threadIdx.x;
  const int wave = tid >> 6, lane = tid & 63;
  const int lid = blockIdx.x;                    // [0,512)
  const int xcd = lid & 7, cch = lid >> 3;
  const int bx = xcd * 8 + (cch & 7), by = cch >> 3;
  const int row0 = bx * 128, col0 = by * 128;
  const int wm = (wave & 1) * 64, wn = (wave >> 1) * 64;
  const int fr = lane & 15, qd = lane >> 4;
  const int srow = lane >> 3;
  const int scol = ((lane & 7) ^ srow) << 3;

  f32x4 acc[4][4] = {};
  const u16* pA = A  + (size_t)(row0 + wave * 32 + srow) * K + scol;
  const u16* pB = Bw + (size_t)(col0 + wave * 32 + srow) * K + scol;

  for (int k0 = 0; k0 < K; k0 += BK) {
#pragma unroll
    for (int c = 0; c < 4; ++c) {
      gl2lds16(pA + (size_t)(c * 8) * K + k0, &As[(wave * 32 + c * 8) * 64]);
      gl2lds16(pB + (size_t)(c * 8) * K + k0, &Bs[(wave * 32 + c * 8) * 64]);
    }
    __syncthreads();
#pragma unroll
    for (int kk = 0; kk < 2; ++kk) {
      bf16x8 af[4], bf[4];
#pragma unroll
      for (int i = 0; i < 4; ++i) {
        int ra = wm + i * 16 + fr;
        af[i] = *reinterpret_cast<const bf16x8*>(
            &As[ra * 64 + (((kk * 4 + qd) ^ (ra & 7)) << 3)]);
        int rb = wn + i * 16 + fr;
        bf[i] = *reinterpret_cast<const bf16x8*>(
            &Bs[rb * 64 + (((kk * 4 + qd) ^ (rb & 7)) << 3)]);
      }
#pragma unroll
      for (int i = 0; i < 4; ++i)
#pragma unroll
        for (int j = 0; j < 4; ++j)
          acc[i][j] = __builtin_amdgcn_mfma_f32_16x16x32_bf16(af[i], bf[j], acc[i][j], 0, 0, 0);
    }
    __syncthreads();
  }

#pragma unroll
  for (int j = 0; j < 4; ++j) {
    int col = col0 + wn + j * 16 + fr;
    float bv = bias[col];
#pragma unroll
    for (int i = 0; i < 4; ++i) {
      int rowb = row0 + wm + i * 16 + (lane >> 4) * 4;
#pragma unroll
      for (int r = 0; r < 4; ++r)
        Cout[(size_t)(rowb + r) * N + col] = acc[i][j][r] + bv;
    }
  }
}

// ---------------- attention: 32x32x16 MFMA, KVBLK=64, VALU diet (round-4) ----
// Wave w owns (qt = w>>1, key-half kh = w&1): 32 keys x 32 queries per tile.
// Double-buffered K/V (32KB LDS) via global_load_lds, pre-swizzled global src.
// P->bf16 via HW v_cvt_pk_bf16_f32 (T12); s_setprio(1) through compute (T5).
__global__ __launch_bounds__(256, 4)
void attn_kernel(const u16* __restrict__ Q, const u16* __restrict__ Kmat,
                 const u16* __restrict__ VT, u16* __restrict__ O) {
  // buf b at smem + b*16384: Ks[64][64] u16 (8KB, chunk^(key&7)),
  //                          Vs[64][64] u16 (8KB, chunk^(d&7))
  // epilogue aliases: OfT[64][68] f32 (17408B) + Qs[128] f32 (512B)
  __shared__ alignas(16) unsigned char smem[32768];
  float* OfT = (float*)smem;
  float* Qs  = (float*)(smem + 17408);

  const int tid = threadIdx.x, wave = tid >> 6, lane = tid & 63;
  const int l31 = lane & 31, hi = lane >> 5;
  const int qt = wave >> 1, kh = wave & 1;
  const int bh = blockIdx.x, qt0 = blockIdx.y;
  const int b = bh >> 4, h = bh & 15;
  const size_t base = (size_t)b * Tt * Cc + (size_t)h * Dd;
  const size_t vtb = (size_t)bh * Dd * Tt;

  // Q fragments (own qt only): B-operand B[k=d][n=q], lane holds
  // Q[q = qt*32 + l31][d = c*16 + hi*8 + j]
  bf16x8 qb[4];
  {
    const u16* qp = Q + base + (size_t)(qt0 * 64 + qt * 32 + l31) * Cc + hi * 8;
#pragma unroll
    for (int c = 0; c < 4; ++c)
      qb[c] = *reinterpret_cast<const bf16x8*>(qp + c * 16);
  }

  f32x16 Oacc[2] = {};       // [dh]: O[q = qt*32 + crow][d = dh*32 + l31] (kh slice)
  f32x2 sacc = {0.f, 0.f};

  // Pre-swizzled per-lane global pointers; staging lane-pattern identical for K,V:
  // instr (w,c) covers 8 LDS rows (w*16 + c*8 + L>>3), chunk ci = L&7,
  // source chunk = ci ^ (row&7) = (L&7)^(L>>3).
  const u16* pK = Kmat + base + (size_t)(wave * 16 + (lane >> 3)) * Cc +
                  (((lane & 7) ^ (lane >> 3)) << 3);
  const u16* pV = VT + vtb + (size_t)(wave * 16 + (lane >> 3)) * Tt +
                  (((lane & 7) ^ (lane >> 3)) << 3);

  auto STAGE = [&](int buf, int kt) {
    u16* Kd = (u16*)(smem + (buf << 14)) + wave * 1024;
    u16* Vd = Kd + 4096;   // V region = K region + 8KB
    const u16* pk = pK + (size_t)kt * Cc;
    const u16* pv = pV + kt;
#pragma unroll
    for (int c = 0; c < 2; ++c) {
      gl2lds16(pk + (size_t)(c * 8) * Cc, Kd + c * 512);
      gl2lds16(pv + (size_t)(c * 8) * Tt, Vd + c * 512);
    }
  };

  STAGE(0, 0);
  __syncthreads();

  int cur = 0;
#pragma unroll 1
  for (int t = 0; t < 32; ++t) {
    if (t < 31) STAGE(cur ^ 1, (t + 1) << 6);

    const u16* Ks = (const u16*)(smem + (cur << 14));
    const u16* Vs = Ks + 4096;

    // K A-frags: A[row = key = kh*32 + l31][k = c*16 + hi*8 + j]
    bf16x8 ka[4], vb[2][2];
    const int key = kh * 32 + l31;
#pragma unroll
    for (int c = 0; c < 4; ++c)
      ka[c] = *reinterpret_cast<const bf16x8*>(
          &Ks[key * 64 + ((((c << 1) + hi) ^ (key & 7)) << 3)]);
    // V B-frags: B[k = kh*32 + k0i*16 + hi*8 + j][n = d = dh*32 + l31]
#pragma unroll
    for (int k0i = 0; k0i < 2; ++k0i)
#pragma unroll
      for (int dh = 0; dh < 2; ++dh) {
        int drow = dh * 32 + l31;
        int ch = kh * 4 + k0i * 2 + hi;
        vb[k0i][dh] = *reinterpret_cast<const bf16x8*>(
            &Vs[drow * 64 + ((ch ^ (drow & 7)) << 3)]);
      }

    __builtin_amdgcn_s_setprio(1);

    // S^T[key][q]: lane holds s[reg] at key = kh*32 + (reg&3)+8*(reg>>2)+4*hi, q=l31
    f32x16 s = {};
#pragma unroll
    for (int c = 0; c < 4; ++c)
      s = __builtin_amdgcn_mfma_f32_32x32x16_bf16(ka[c], qb[c], s, 0, 0, 0);
    unsigned pk8[8];   // pk8[i] = bf16 pair, local keys 8*(i>>1) + 4*hi + 2*(i&1) + {0,1}
#pragma unroll
    for (int i = 0; i < 8; ++i) {
      float p0 = EXP2F(s[2 * i]), p1 = EXP2F(s[2 * i + 1]);
      sacc += (f32x2){p0, p1};                 // v_pk_add_f32
      pk8[i] = cvt_pk_bf16(p0, p1);            // 1 inst (HW packed cvt)
    }
    // assemble PV A-frags: lane needs P[q=l31][local keys k0 + hi*8 + 0..7]
    unsigned a0 = pk8[0], a1 = pk8[1], a2 = pk8[2], a3 = pk8[3];
    unsigned b0 = pk8[4], b1 = pk8[5], b2 = pk8[6], b3 = pk8[7];
    PERMLANE32_SWAP(a0, a2);   // -> words 0,2 of keys[0..15] frag
    PERMLANE32_SWAP(a1, a3);   // -> words 1,3
    PERMLANE32_SWAP(b0, b2);   // -> words 0,2 of keys[16..31] frag
    PERMLANE32_SWAP(b1, b3);
    union { unsigned u[4]; bf16x8 v; } plo, phi;
    plo.u[0] = a0; plo.u[1] = a1; plo.u[2] = a2; plo.u[3] = a3;
    phi.u[0] = b0; phi.u[1] = b1; phi.u[2] = b2; phi.u[3] = b3;
    Oacc[0] = __builtin_amdgcn_mfma_f32_32x32x16_bf16(plo.v, vb[0][0], Oacc[0], 0, 0, 0);
    Oacc[1] = __builtin_amdgcn_mfma_f32_32x32x16_bf16(plo.v, vb[0][1], Oacc[1], 0, 0, 0);
    Oacc[0] = __builtin_amdgcn_mfma_f32_32x32x16_bf16(phi.v, vb[1][0], Oacc[0], 0, 0, 0);
    Oacc[1] = __builtin_amdgcn_mfma_f32_32x32x16_bf16(phi.v, vb[1][1], Oacc[1], 0, 0, 0);

    __builtin_amdgcn_s_setprio(0);

    __syncthreads();
    cur ^= 1;
  }

  // ---- denominators: cross-hi reduce, one 32-slot row per wave ----
  {
    float s = sacc[0] + sacc[1];
    s += __shfl_xor(s, 32, 64);
    if (hi == 0) Qs[wave * 32 + l31] = s;
  }

  // ---- combine partial O across key-halves into OfT[d][q] (2 barriers) ----
  // kh=0 waves (0:qt0, 2:qt1) write disjoint column ranges; kh=1 accumulate.
#pragma unroll
  for (int step = 0; step < 2; ++step) {
    if (kh == step) {
#pragma unroll
      for (int dh = 0; dh < 2; ++dh) {
        int d = dh * 32 + l31;
        float* rowp = &OfT[d * 68 + qt * 32 + hi * 4];
#pragma unroll
        for (int g = 0; g < 4; ++g) {
          f32x4 v;
          v[0] = Oacc[dh][g * 4 + 0]; v[1] = Oacc[dh][g * 4 + 1];
          v[2] = Oacc[dh][g * 4 + 2]; v[3] = Oacc[dh][g * 4 + 3];
          float* dst = rowp + g * 8;   // q = qt*32 + 4*hi + 8*g + {0..3}
          if (step == 0) *reinterpret_cast<f32x4*>(dst) = v;
          else {
            f32x4 old = *reinterpret_cast<const f32x4*>(dst);
            *reinterpret_cast<f32x4*>(dst) = old + v;
          }
        }
      }
    }
    __syncthreads();
  }

  // ---- normalize + store ----
  {
    int q = tid >> 2, dg = tid & 3;
    float qtot = Qs[(q >> 5) * 64 + (q & 31)] + Qs[(q >> 5) * 64 + 32 + (q & 31)];
    float linv = 1.0f / qtot;
    alignas(16) u16 tmp[16];
#pragma unroll
    for (int i = 0; i < 16; ++i)
      tmp[i] = f32_to_bf16(OfT[(dg * 16 + i) * 68 + q] * linv);
    u16* op = O + base + (size_t)(qt0 * 64 + q) * Cc + dg * 16;
    *reinterpret_cast<uint4*>(op)     = *reinterpret_cast<const uint4*>(tmp);
    *reinterpret_cast<uint4*>(op + 8) = *reinterpret_cast<const uint4*>(tmp + 8);
  }
}

extern "C" void kernel_launch(void* const* d_in, const int* in_sizes, int n_in,
                              void* d_out, int out_size, void* d_ws, size_t ws_size,
                              hipStream_t stream) {
  const float* x  = (const float*)d_in[0];
  const float* Wq = (const float*)d_in[1];
  const float* bq = (const float*)d_in[2];
  const float* Wk = (const float*)d_in[3];
  const float* bk = (const float*)d_in[4];
  const float* Wv = (const float*)d_in[5];
  const float* bv = (const float*)d_in[6];
  const float* Wo = (const float*)d_in[7];
  const float* bo = (const float*)d_in[8];

  const size_t NX = (size_t)Bb * Tt * Cc;  // 8388608
  const size_t NW = (size_t)Cc * Cc;       // 1048576

  u16* ws  = (u16*)d_ws;
  u16* xb  = ws;
  u16* wqb = ws + NX;     // wq|wk|wv contiguous -> the fused [3072,1024] B matrix
  u16* wkb = wqb + NW;
  u16* wvb = wkb + NW;
  u16* wob = wvb + NW;
  u16* qb  = wob + NW;
  u16* kb  = qb + NX;
  u16* vtb = kb + NX;
  u16* attnb = xb;  // alias: x dead once projections are done

  cast_all<<<dim3(12288), 256, 0, stream>>>(x, Wq, Wk, Wv, Wo, ws);

  const float QSCL = 0.125f * 1.44269504f;  // 1/sqrt(D) * log2(e), folded into Q
  gemm_qkv<<<dim3(1536), 256, 0, stream>>>(xb, wqb, bq, bk, bv, qb, kb, vtb, QSCL);

  attn_kernel<<<dim3(Bb * Hh, Tt / 64), 256, 0, stream>>>(qb, kb, vtb, attnb);

  gemm_out<<<dim3(512), 256, 0, stream>>>(attnb, wob, bo, (float*)d_out,
                                          Bb * Tt, Cc, Cc);
}